// Round 11
// baseline (259.844 us; speedup 1.0000x reference)
//
#include <hip/hip_runtime.h>
#include <hip/hip_bf16.h>
#include <stdint.h>
#include <stddef.h>

// Problem constants (fixed by the reference)
#define BB 2
#define NSEQ 2048
#define DM 1024
#define H 16
#define HD 128
#define D1 2048
#define NKI 16
#define RANKI 32
#define MROWS (BB * NSEQ)   // 4096 rows for all GEMMs
#define VPROWS 6144         // 2048 zero-pad | 2048 data | 2048 zero-pad
#define NTAP 28
#define NPAIR 13
#define NCHUNK 128
#define CLEN 16
#define NSEG 16             // R22: segments in the chunk-state scan
#define SEGC (NCHUNK / NSEG)   // 8 chunks per segment
#define GAMMA_F 0.999f
#define G_CL 0.9841201f     // 0.999^16 (chunk-length homogeneous decay)
#define G_SC8 0.87979895f   // 0.999^128 = G_CL^8 (segment-length decay)
#define LN_G (-1.00050033e-3f)

// NOTE: delta must remain fp32 everywhere [R9]. No 32x32x16 MFMA [R13].
// LEDGERS (do not re-open without new evidence):
//  SCAN: R18 zero-row redirect = best (~48.5us). R17 branch-skip FAILED (152),
//    R19 2-chunk MLP NEUTRAL, R20 explicit pipeline FAILED (65). Parked.
//  UV GEMM: gemm_uv8 256^2/BK64/8-wave counted-vmcnt = best (~46us). R15
//    MTILES=4 neutral; R23 ring-3 (32 MFMA/wave/tile) REGRESSED +6.4 --
//    per-wave MFMA per barrier is the dominant knob. Parked.
//  OUT GEMM: gemm_out2 128^2/8-wave = best (~30us). R24 4-wave/2-blocks-CU
//    out3 REGRESSED +5. Parked.
//  R24 rocprof was clock-contaminated (uv8 "78us" inconsistent with total);
//    per-kernel durs that round discarded.
// R22 WIN: segmented state scan (B1 local prefixes + B2 A^8 scan + correction
//   folded into combine).
// R25: (a) out2 restored; (b) combine 4->8 ch/thread (uint4 bf16 streams,
//   2xfloat4 states, expf amortized; op order bit-identical); (c) prep merged
//   into wprep (blocks [6176,10273)) -- one fewer dispatch.
__device__ constexpr int TAPS[NTAP] = {
  1, 2, 138, 139, 274, 275, 411, 412, 547, 548, 684,
  820, 821, 956, 957, 1093, 1094, 1229, 1230, 1366,
  1502, 1503, 1638, 1639, 1775, 1776, 1911, 1912};
__device__ constexpr int LEADL[NPAIR] = {1, 138, 274, 411, 547, 820, 956, 1093, 1229, 1502, 1638, 1775, 1911};
__device__ constexpr int LEADI[NPAIR] = {0, 2, 4, 6, 8, 11, 13, 15, 17, 20, 22, 24, 26};
#define SGL0_L 684
#define SGL0_I 10
#define SGL1_L 1366
#define SGL1_I 19

typedef short short8 __attribute__((ext_vector_type(8)));
typedef float floatx4 __attribute__((ext_vector_type(4)));

__device__ __forceinline__ float bf2f(unsigned short u) {
  union { unsigned int i; float f; } v; v.i = ((unsigned int)u) << 16; return v.f;
}
__device__ __forceinline__ unsigned short f2bf(float f) {
  union { float f; unsigned int i; } v; v.f = f;
  unsigned int r = (v.i + 0x7FFFu + ((v.i >> 16) & 1u)) >> 16;
  return (unsigned short)r;
}
__device__ __forceinline__ float bflo(unsigned int p) {
  union { unsigned int i; float f; } v; v.i = p << 16; return v.f;
}
__device__ __forceinline__ float bfhi(unsigned int p) {
  union { unsigned int i; float f; } v; v.i = p & 0xffff0000u; return v.f;
}
// async 16B global->LDS DMA: lane i lands at (wave-uniform) l + i*16 bytes
__device__ __forceinline__ void async16(const unsigned short* g, unsigned short* l) {
  __builtin_amdgcn_global_load_lds(
      (const __attribute__((address_space(1))) unsigned int*)g,
      (__attribute__((address_space(3))) unsigned int*)l, 16, 0, 0);
}

#define CVT4 (MROWS * DM / 4)            // 1048576 float4->ushort4 units
#define WPREP_BLKS (6176 + CVT4 / 256 + 1)   // 10273

// ---- K(l) = interp(kind, l) * gamma^l on an LDS copy of kind --------------
__device__ __forceinline__ float KinterpL(const float* kk, int l, int d) {
  if (l < 1) return 0.0f;   // l > 2047 never queried (max tap 1912)
  float p = (float)(l - 1) * (15.0f / 2046.0f);
  int lo = (int)p; if (lo > 15) lo = 15;
  int hi = lo + 1; if (hi > 15) hi = 15;
  float w = p - (float)lo;
  float v = kk[lo * HD + d] * (1.0f - w) + kk[hi * HD + d] * w;
  return v * __powf(GAMMA_F, (float)l);
}

// ---- fused prep: Wo^T | Wu/Wv^T | kdtab | x->bf16 + zero-row [R25] --------
// blockIdx.x: [0,2048) Wo tiles; [2048,6144) uv tiles; [6144,6176) kdtab;
// [6176, WPREP_BLKS) x-convert + 4KB zero-row.
__global__ __launch_bounds__(256) void wprep_kernel(const float* __restrict__ Wu,
                                                    const float* __restrict__ Wv,
                                                    const float* __restrict__ Wo,
                                                    unsigned short* __restrict__ WT2,
                                                    unsigned short* __restrict__ WoT,
                                                    const float* __restrict__ ap,
                                                    const float* __restrict__ bp,
                                                    const float* __restrict__ an,
                                                    const float* __restrict__ bn,
                                                    float* __restrict__ dtp,
                                                    float* __restrict__ dtn,
                                                    const float* __restrict__ x,
                                                    unsigned short* __restrict__ x_bf,
                                                    unsigned short* __restrict__ zrow) {
  int blk = blockIdx.x;
  int tid = threadIdx.x;
  if (blk < 6144) {
    __shared__ unsigned short t[32][33];
    const float* in; unsigned short* out;
    int rows, cols, bx, by;
    if (blk < 2048) {           // Wo [D1][DM] -> WoT [DM][D1]
      in = Wo; out = WoT; rows = D1; cols = DM;
      bx = (blk & 31) * 32; by = (blk >> 5) * 32;
    } else {                    // Wu/Wv [DM][D1] -> WT2 [2*D1][DM]
      int local = blk - 2048;
      int z = local >> 11, l2 = local & 2047;
      in = z ? Wv : Wu; out = WT2 + (size_t)z * D1 * DM;
      rows = DM; cols = D1;
      bx = (l2 & 63) * 32; by = (l2 >> 6) * 32;
    }
    int tx = tid & 31, ty = tid >> 5;   // (32,8) flattened
#pragma unroll
    for (int j = 0; j < 32; j += 8)
      t[ty + j][tx] = f2bf(in[(size_t)(by + ty + j) * cols + bx + tx]);
    __syncthreads();
#pragma unroll
    for (int j = 0; j < 32; j += 8)
      out[(size_t)(bx + ty + j) * rows + by + tx] = t[tx][ty + j];
  } else if (blk < 6176) {      // kdtab: 32 blocks = (h, dir)
    __shared__ float kk[NKI * HD];  // 8 KB
    int e0 = blk - 6144;
    int h = e0 & 15, dir = e0 >> 4;
    const float* a = (dir ? an : ap) + h * NKI * RANKI;
    const float* b = (dir ? bn : bp) + h * RANKI * HD;
    for (int e = tid; e < NKI * HD; e += 256) {
      int k = e >> 7, d = e & 127;
      float s = 0.0f;
#pragma unroll
      for (int r = 0; r < RANKI; ++r) s += a[k * RANKI + r] * b[r * HD + d];
      kk[e] = s;
    }
    __syncthreads();
    float* dt = (dir ? dtn : dtp) + (size_t)h * NTAP * HD;
    for (int e = tid; e < NTAP * HD; e += 256) {
      int j = e >> 7, d = e & 127;
      int l = TAPS[j];
      float K0 = KinterpL(kk, l, d);
      float K1 = KinterpL(kk, l - 1, d);
      float K2 = KinterpL(kk, l - 2, d);
      dt[e] = K0 - 2.0f * GAMMA_F * K1 + (GAMMA_F * GAMMA_F) * K2;
    }
  } else {                      // x fp32->bf16 + zero-row [R25 merge]
    int i = (blk - 6176) * 256 + tid;
    if (i < CVT4) {
      float4 f = ((const float4*)x)[i];
      ushort4 o;
      o.x = f2bf(f.x); o.y = f2bf(f.y); o.z = f2bf(f.z); o.w = f2bf(f.w);
      ((ushort4*)x_bf)[i] = o;
    } else {
      int j = i - CVT4;
      if (j < 256) {
        uint4 z; z.x = z.y = z.z = z.w = 0u;
        ((uint4*)zrow)[j] = z;
      }
    }
  }
}

// ======== uv GEMM, R16/R19 (proven best): 256x256, BK=64, 8 waves ==========
// C = silu(A @ Bt^T + bias), fused u|v (N=4096): n0>=2048 -> Vp row-remapped.
// LDS: 2 K-tile buffers x (A 256x64 | B 256x64) bf16 = 128 KB, 1 block/CU.
// Swizzle (both-sides, involution): stage src col ((lane&7)^srow)*8, read
// chunk (kk*4+q)^(l16&7). B-frags hoisted (mh-invariant). 64 MFMA/wave/tile.
__global__ __launch_bounds__(512) void gemm_uv8(const unsigned short* __restrict__ A,
                                                const unsigned short* __restrict__ Bt,
                                                const float* __restrict__ bu,
                                                const float* __restrict__ bv,
                                                unsigned short* __restrict__ U,
                                                unsigned short* __restrict__ Vp) {
  __shared__ unsigned short lds[65536];   // 128 KB
  constexpr int K = DM;        // 1024
  constexpr int NT = K / 64;   // 16 K-tiles
  // bijective XCD swizzle: 256 blocks = 8 XCDs x 32
  int lin = blockIdx.y * 16 + blockIdx.x;
  int swz = (lin & 7) * 32 + (lin >> 3);
  int n0 = (swz & 15) * 256;
  int m0 = (swz >> 4) * 256;
  int tid = threadIdx.x;
  int lane = tid & 63, w = tid >> 6;
  int wm = w >> 2, wn = w & 3;            // 2M x 4N wave grid
  int q = lane >> 4, l16 = lane & 15;
  // ---- staging addressing (pre-swizzled global source) ----
  int srow = lane >> 3;                       // 0..7
  int soff = ((lane & 7) ^ srow) << 3;        // swizzled 8-elem chunk
  const unsigned short* Ab = A + (size_t)(m0 + w * 8 + srow) * K + soff;
  const unsigned short* Bb = Bt + (size_t)(n0 + w * 8 + srow) * K + soff;
  unsigned aoff0 = w * 512;                   // elems; +p*16384; +4096 per 64 rows
  unsigned boff0 = 32768u + w * 512;
  // ---- read addressing ----
  int swk0 = (q ^ (l16 & 7)) << 3;            // kk=0 chunk offset (elems)
  int swk1 = ((4 | q) ^ (l16 & 7)) << 3;      // kk=1
  int pAr = wm * 8192;                        // my A half slot (+p*16384)
  int pBr = 32768 + (wn >> 1) * 8192;         // my B half slot (+p*16384)
  int rB0 = (wn & 1) * 64;                    // row base within B half

  floatx4 acc[8][4];
#pragma unroll
  for (int f = 0; f < 8; ++f)
#pragma unroll
    for (int g = 0; g < 4; ++g) acc[f][g] = (floatx4){0.f, 0.f, 0.f, 0.f};

  auto stage = [&](int p, int t) {
    const unsigned short* a = Ab + t * 64;
    const unsigned short* b = Bb + t * 64;
    unsigned ao = aoff0 + p * 16384;
    unsigned bo = boff0 + p * 16384;
    async16(a,               &lds[ao]);
    async16(a + (size_t)64 * K,  &lds[ao + 4096]);
    async16(a + (size_t)128 * K, &lds[ao + 8192]);
    async16(a + (size_t)192 * K, &lds[ao + 12288]);
    async16(b,               &lds[bo]);
    async16(b + (size_t)64 * K,  &lds[bo + 4096]);
    async16(b + (size_t)128 * K, &lds[bo + 8192]);
    async16(b + (size_t)192 * K, &lds[bo + 12288]);
  };

  // prologue: tiles 0 and 1 in flight; wait for tile 0 everywhere
  stage(0, 0);
  stage(1, 1);
  asm volatile("s_waitcnt vmcnt(8)" ::: "memory");
  __builtin_amdgcn_s_barrier();

  for (int t = 0; t < NT; ++t) {
    int p = t & 1;
    const unsigned short* As = &lds[pAr + p * 16384];
    const unsigned short* Bs = &lds[pBr + p * 16384];
    short8 bfr[4][2];
#pragma unroll
    for (int g = 0; g < 4; ++g) {
      int rh = (rB0 + g * 16 + l16) * 64;
      bfr[g][0] = *(const short8*)(Bs + rh + swk0);
      bfr[g][1] = *(const short8*)(Bs + rh + swk1);
    }
#pragma unroll
    for (int mh = 0; mh < 2; ++mh) {
      short8 af[4][2];
#pragma unroll
      for (int f = 0; f < 4; ++f) {
        int rh = ((mh * 4 + f) * 16 + l16) * 64;
        af[f][0] = *(const short8*)(As + rh + swk0);
        af[f][1] = *(const short8*)(As + rh + swk1);
      }
      __builtin_amdgcn_s_setprio(1);
#pragma unroll
      for (int f = 0; f < 4; ++f)
#pragma unroll
        for (int g = 0; g < 4; ++g) {
          acc[mh * 4 + f][g] = __builtin_amdgcn_mfma_f32_16x16x32_bf16(
              af[f][0], bfr[g][0], acc[mh * 4 + f][g], 0, 0, 0);
          acc[mh * 4 + f][g] = __builtin_amdgcn_mfma_f32_16x16x32_bf16(
              af[f][1], bfr[g][1], acc[mh * 4 + f][g], 0, 0, 0);
        }
      __builtin_amdgcn_s_setprio(0);
    }
    if (t == NT - 1) break;
    asm volatile("" ::: "memory");          // keep LDS reads above barrier1
    __builtin_amdgcn_s_barrier();           // all reads of buf p done
    if (t + 2 < NT) {
      stage(p, t + 2);                      // refill freed buffer
      asm volatile("s_waitcnt vmcnt(8)" ::: "memory");  // tile t+1 landed (mine)
    } else {
      asm volatile("s_waitcnt vmcnt(0)" ::: "memory");  // final drain
    }
    __builtin_amdgcn_s_barrier();           // everyone's tile t+1 landed
  }

  // epilogue: D[row = q*4 + r][col = l16] per 16x16 frag (verified mapping)
  int isv = (n0 >= 2048);
  const float* bias = isv ? bv : bu;
#pragma unroll
  for (int f = 0; f < 8; ++f) {
#pragma unroll
    for (int g = 0; g < 4; ++g) {
      int n = n0 + wn * 64 + g * 16 + l16;
      int nc = isv ? (n - 2048) : n;
      float bsv = bias[nc];
#pragma unroll
      for (int r = 0; r < 4; ++r) {
        int m = m0 + wm * 128 + f * 16 + q * 4 + r;
        float val = acc[f][g][r] + bsv;
        val = val / (1.0f + __expf(-val));
        if (isv) {
          size_t mrow = (size_t)(2048 + m + ((m >> 11) << 12));  // padded-V row
          Vp[mrow * 2048 + nc] = f2bf(val);
        } else {
          U[(size_t)m * 2048 + nc] = f2bf(val);
        }
      }
    }
  }
}

// ======== out GEMM, R21 (proven best): 128x128, BK=64, 8 waves =============
// C(fp32) = A @ Bt^T + bias. M=4096 N=1024 K=2048. 2-buf LDS (64 KB),
// stage(t+2) at boundary, vmcnt(4), both-sides XOR swizzle, XCD swizzle.
// Wave grid 4M x 2N; wave output 32x64 (acc[2][4]).
__global__ __launch_bounds__(512) void gemm_out2(const unsigned short* __restrict__ A,
                                                 const unsigned short* __restrict__ Bt,
                                                 const float* __restrict__ bias,
                                                 float* __restrict__ C) {
  __shared__ unsigned short lds[32768];   // 64 KB
  constexpr int K = D1;        // 2048
  constexpr int NT = K / 64;   // 32 K-tiles
  // bijective XCD swizzle: 256 blocks = 8 XCDs x 32
  int lin = blockIdx.y * 8 + blockIdx.x;     // grid (8, 32)
  int swz = (lin & 7) * 32 + (lin >> 3);
  int n0 = (swz & 7) * 128;                  // 8 n-tiles
  int m0 = (swz >> 3) * 128;                 // 32 m-tiles
  int tid = threadIdx.x;
  int lane = tid & 63, w = tid >> 6;
  int wm = w >> 1, wn = w & 1;               // 4M x 2N wave grid
  int q = lane >> 4, l16 = lane & 15;
  // staging (pre-swizzled global source)
  int srow = lane >> 3;
  int soff = ((lane & 7) ^ srow) << 3;
  const unsigned short* Ab = A + (size_t)(m0 + w * 8 + srow) * K + soff;
  const unsigned short* Bb = Bt + (size_t)(n0 + w * 8 + srow) * K + soff;
  unsigned aoff0 = w * 512;                  // +p*8192; +4096 per 64 rows
  unsigned boff0 = 16384u + w * 512;
  // read addressing
  int swk0 = (q ^ (l16 & 7)) << 3;
  int swk1 = ((4 | q) ^ (l16 & 7)) << 3;

  floatx4 acc[2][4];
#pragma unroll
  for (int f = 0; f < 2; ++f)
#pragma unroll
    for (int g = 0; g < 4; ++g) acc[f][g] = (floatx4){0.f, 0.f, 0.f, 0.f};

  auto stage = [&](int p, int t) {
    const unsigned short* a = Ab + t * 64;
    const unsigned short* b = Bb + t * 64;
    unsigned ao = aoff0 + p * 8192;
    unsigned bo = boff0 + p * 8192;
    async16(a,                  &lds[ao]);
    async16(a + (size_t)64 * K, &lds[ao + 4096]);
    async16(b,                  &lds[bo]);
    async16(b + (size_t)64 * K, &lds[bo + 4096]);
  };

  stage(0, 0);
  stage(1, 1);
  asm volatile("s_waitcnt vmcnt(4)" ::: "memory");
  __builtin_amdgcn_s_barrier();

  for (int t = 0; t < NT; ++t) {
    int p = t & 1;
    const unsigned short* As = &lds[p * 8192];
    const unsigned short* Bs = &lds[16384 + p * 8192];
    short8 af[2][2], bfr[4][2];
#pragma unroll
    for (int g = 0; g < 4; ++g) {
      int rh = (wn * 64 + g * 16 + l16) * 64;
      bfr[g][0] = *(const short8*)(Bs + rh + swk0);
      bfr[g][1] = *(const short8*)(Bs + rh + swk1);
    }
#pragma unroll
    for (int f = 0; f < 2; ++f) {
      int rh = (wm * 32 + f * 16 + l16) * 64;
      af[f][0] = *(const short8*)(As + rh + swk0);
      af[f][1] = *(const short8*)(As + rh + swk1);
    }
    __builtin_amdgcn_s_setprio(1);
#pragma unroll
    for (int f = 0; f < 2; ++f)
#pragma unroll
      for (int g = 0; g < 4; ++g) {
        acc[f][g] = __builtin_amdgcn_mfma_f32_16x16x32_bf16(
            af[f][0], bfr[g][0], acc[f][g], 0, 0, 0);
        acc[f][g] = __builtin_amdgcn_mfma_f32_16x16x32_bf16(
            af[f][1], bfr[g][1], acc[f][g], 0, 0, 0);
      }
    __builtin_amdgcn_s_setprio(0);
    if (t == NT - 1) break;
    asm volatile("" ::: "memory");
    __builtin_amdgcn_s_barrier();           // all reads of buf p done
    if (t + 2 < NT) {
      stage(p, t + 2);
      asm volatile("s_waitcnt vmcnt(4)" ::: "memory");  // tile t+1 landed (mine)
    } else {
      asm volatile("s_waitcnt vmcnt(0)" ::: "memory");
    }
    __builtin_amdgcn_s_barrier();           // everyone's tile t+1 landed
  }

  // epilogue: D[row = q*4 + r][col = l16] per 16x16 frag
#pragma unroll
  for (int f = 0; f < 2; ++f) {
#pragma unroll
    for (int g = 0; g < 4; ++g) {
      int n = n0 + wn * 64 + g * 16 + l16;
      float bsv = bias[n];
#pragma unroll
      for (int r = 0; r < 4; ++r) {
        int m = m0 + wm * 32 + f * 16 + q * 4 + r;
        C[(size_t)m * DM + n] = acc[f][g][r] + bsv;
      }
    }
  }
}

// ---------------- chunked IIR scan (phase A) -------------------------------
// R18 VERBATIM (best measured: ~48.5us). Unconditional loads; OOB rows ->
// shared zero-row (uniform base select). Do not re-schedule [ledger].
__global__ __launch_bounds__(256, 1) void scan_chunks(const unsigned short* __restrict__ Vp,
                                                      const unsigned short* __restrict__ zr,
                                                      const float* __restrict__ dp,
                                                      const float* __restrict__ dn,
                                                      unsigned short* __restrict__ ypl,
                                                      unsigned short* __restrict__ ynl,
                                                      float* __restrict__ Sy_ex,
                                                      float* __restrict__ SG_ex) {
  int z = blockIdx.z;            // dir*2 + b
  int dir = z >> 1, b = z & 1;
  int chunk = blockIdx.y;
  int c0 = blockIdx.x * 512 + threadIdx.x * 2;   // two channels per thread
  int h = c0 >> 7, d = c0 & 127;
  const float* dt = (dir ? dn : dp) + ((size_t)h * NTAP) * HD + d;
  float2 dreg[NTAP];
#pragma unroll
  for (int j = 0; j < NTAP; ++j) dreg[j] = *(const float2*)(dt + j * HD);
  // uniform data-region row-0 base (without the per-lane c0)
  const unsigned short* Vd = Vp + (size_t)b * VPROWS * D1 + (size_t)2048 * D1;
  unsigned short* yl = (dir ? ynl : ypl) + (size_t)b * NSEQ * D1 + c0;
  float sy0 = 0.f, sy1 = 0.f, sg0 = 0.f, sg1 = 0.f;
  float carry0[NPAIR], carry1[NPAIR];
  if (!dir) {
    int t0 = chunk * CLEN;
#pragma unroll
    for (int p = 0; p < NPAIR; ++p) {
      int tr = t0 - 1 - LEADL[p];
      const unsigned short* rb = (tr >= 0) ? (Vd + (size_t)tr * D1) : zr;
      unsigned int pk = *(const unsigned int*)(rb + c0);
      carry0[p] = bflo(pk); carry1[p] = bfhi(pk);
    }
    for (int i = 0; i < CLEN; ++i) {
      int t = t0 + i;
      float F0 = 0.f, F1 = 0.f;
#pragma unroll
      for (int p = 0; p < NPAIR; ++p) {
        int tr = t - LEADL[p];
        const unsigned short* rb = (tr >= 0) ? (Vd + (size_t)tr * D1) : zr;
        unsigned int pk = *(const unsigned int*)(rb + c0);
        float vl0 = bflo(pk), vl1 = bfhi(pk);
        F0 += dreg[LEADI[p]].x * vl0 + dreg[LEADI[p] + 1].x * carry0[p];
        F1 += dreg[LEADI[p]].y * vl1 + dreg[LEADI[p] + 1].y * carry1[p];
        carry0[p] = vl0; carry1[p] = vl1;
      }
      {
        int tr = t - SGL0_L;
        const unsigned short* rb = (tr >= 0) ? (Vd + (size_t)tr * D1) : zr;
        unsigned int pk = *(const unsigned int*)(rb + c0);
        F0 += dreg[SGL0_I].x * bflo(pk); F1 += dreg[SGL0_I].y * bfhi(pk);
      }
      {
        int tr = t - SGL1_L;
        const unsigned short* rb = (tr >= 0) ? (Vd + (size_t)tr * D1) : zr;
        unsigned int pk = *(const unsigned int*)(rb + c0);
        F0 += dreg[SGL1_I].x * bflo(pk); F1 += dreg[SGL1_I].y * bfhi(pk);
      }
      sg0 = GAMMA_F * sg0 + F0; sy0 = GAMMA_F * sy0 + sg0;
      sg1 = GAMMA_F * sg1 + F1; sy1 = GAMMA_F * sy1 + sg1;
      unsigned int pack = (unsigned int)f2bf(sy0) | ((unsigned int)f2bf(sy1) << 16);
      *(unsigned int*)(yl + (size_t)t * D1) = pack;
    }
  } else {
    int tstart = (NSEQ - 1) - chunk * CLEN;        // reversed time
#pragma unroll
    for (int p = 0; p < NPAIR; ++p) {
      int tr = tstart + 1 + LEADL[p];
      const unsigned short* rb = (tr <= NSEQ - 1) ? (Vd + (size_t)tr * D1) : zr;
      unsigned int pk = *(const unsigned int*)(rb + c0);
      carry0[p] = bflo(pk); carry1[p] = bfhi(pk);
    }
    for (int i = 0; i < CLEN; ++i) {
      int t = tstart - i;
      float F0 = 0.f, F1 = 0.f;
#pragma unroll
      for (int p = 0; p < NPAIR; ++p) {
        int tr = t + LEADL[p];
        const unsigned short* rb = (tr <= NSEQ - 1) ? (Vd + (size_t)tr * D1) : zr;
        unsigned int pk = *(const unsigned int*)(rb + c0);
        float vl0 = bflo(pk), vl1 = bfhi(pk);
        F0 += dreg[LEADI[p]].x * vl0 + dreg[LEADI[p] + 1].x * carry0[p];
        F1 += dreg[LEADI[p]].y * vl1 + dreg[LEADI[p] + 1].y * carry1[p];
        carry0[p] = vl0; carry1[p] = vl1;
      }
      {
        int tr = t + SGL0_L;
        const unsigned short* rb = (tr <= NSEQ - 1) ? (Vd + (size_t)tr * D1) : zr;
        unsigned int pk = *(const unsigned int*)(rb + c0);
        F0 += dreg[SGL0_I].x * bflo(pk); F1 += dreg[SGL0_I].y * bfhi(pk);
      }
      {
        int tr = t + SGL1_L;
        const unsigned short* rb = (tr <= NSEQ - 1) ? (Vd + (size_t)tr * D1) : zr;
        unsigned int pk = *(const unsigned int*)(rb + c0);
        F0 += dreg[SGL1_I].x * bflo(pk); F1 += dreg[SGL1_I].y * bfhi(pk);
      }
      sg0 = GAMMA_F * sg0 + F0; sy0 = GAMMA_F * sy0 + sg0;
      sg1 = GAMMA_F * sg1 + F1; sy1 = GAMMA_F * sy1 + sg1;
      unsigned int pack = (unsigned int)f2bf(sy0) | ((unsigned int)f2bf(sy1) << 16);
      *(unsigned int*)(yl + (size_t)t * D1) = pack;
    }
  }
  size_t sidx = ((size_t)z * NCHUNK + chunk) * D1 + c0;
  Sy_ex[sidx] = sy0; Sy_ex[sidx + 1] = sy1;
  SG_ex[sidx] = sg0; SG_ex[sidx + 1] = sg1;
}

// ------- phase B1 (R22): segment-local chunk-state prefixes ----------------
__global__ __launch_bounds__(256) void state_scan2(const float* __restrict__ Sy_ex,
                                                   const float* __restrict__ SG_ex,
                                                   float* __restrict__ Sy_in,
                                                   float* __restrict__ SG_in,
                                                   float* __restrict__ Xy,
                                                   float* __restrict__ Xg) {
  int idx = blockIdx.x * 256 + threadIdx.x;   // [0, 4*NSEG*D1)
  int c = idx & (D1 - 1);
  int zs = idx >> 11;            // z*NSEG + seg
  int z = zs >> 4, seg = zs & (NSEG - 1);
  float ey = 0.f, eg = 0.f;
#pragma unroll
  for (int m = 0; m < SEGC; ++m) {
    int k = seg * SEGC + m;
    size_t s = ((size_t)z * NCHUNK + k) * D1 + c;
    Sy_in[s] = ey; SG_in[s] = eg;
    float lex = Sy_ex[s], lgx = SG_ex[s];
    ey = lex + G_CL * (ey + (float)CLEN * eg);
    eg = lgx + G_CL * eg;
  }
  size_t xi = (size_t)zs * D1 + c;
  Xy[xi] = ey; Xg[xi] = eg;
}

// ------- phase B2 (R22): scan the 16 segment exits with A^8 ----------------
__global__ __launch_bounds__(256) void seg_scan(const float* __restrict__ Xy,
                                                const float* __restrict__ Xg,
                                                float* __restrict__ Ey,
                                                float* __restrict__ Eg) {
  int idx = blockIdx.x * 256 + threadIdx.x;   // [0, 4*D1)
  int z = idx >> 11, c = idx & (D1 - 1);
  float ey = 0.f, eg = 0.f;
#pragma unroll
  for (int s = 0; s < NSEG; ++s) {
    size_t xi = ((size_t)z * NSEG + s) * D1 + c;
    Ey[xi] = ey; Eg[xi] = eg;
    float xy = Xy[xi], xg = Xg[xi];
    ey = xy + G_SC8 * (ey + 128.0f * eg);
    eg = xg + G_SC8 * eg;
  }
}

// ---------------- combine + gate (phase C), 8 channels/thread [R25] --------
// Sy_in/SG_in hold segment-LOCAL prefixes; correction via A^m and segment
// entry states Ey/Eg (L2-resident). uint4 (16B/lane) bf16 streams; op order
// per channel identical to R22 (bit-exact).
__global__ __launch_bounds__(256) void combine_kernel(const unsigned short* __restrict__ ypl,
                                                      const unsigned short* __restrict__ ynl,
                                                      const unsigned short* __restrict__ Vp,
                                                      const float* __restrict__ Sy_in,
                                                      const float* __restrict__ SG_in,
                                                      const float* __restrict__ Ey,
                                                      const float* __restrict__ Eg,
                                                      const float* __restrict__ tz,
                                                      const unsigned short* __restrict__ U,
                                                      unsigned short* __restrict__ G) {
  int e = blockIdx.x * 256 + threadIdx.x;     // octet index over [b][t][c/8]
  int cq = e & (D1 / 8 - 1);
  int c0 = cq * 8;
  int r = e >> 8;
  int t = r & (NSEQ - 1);
  int b = r >> 11;
  int kp = t >> 4;  float dpD = (float)((t & 15) + 1);
  int tau = (NSEQ - 1) - t;
  int kn = tau >> 4; float dnD = (float)((tau & 15) + 1);
  float gp = __expf(dpD * LN_G);
  float gn = __expf(dnD * LN_G);
  size_t ix = (size_t)r * D1 + c0;
  size_t sp = ((size_t)(b) * NCHUNK + kp) * D1 + c0;          // z = b (pos)
  size_t sn = ((size_t)(2 + b) * NCHUNK + kn) * D1 + c0;      // z = 2+b (neg)
  uint4 pyl = *(const uint4*)(ypl + ix);
  uint4 pyn = *(const uint4*)(ynl + ix);
  uint4 pv  = *(const uint4*)(Vp + ((size_t)b * VPROWS + 2048 + t) * D1 + c0);
  uint4 pu  = *(const uint4*)(U + ix);
  float4 syp0 = *(const float4*)(Sy_in + sp);
  float4 syp1 = *(const float4*)(Sy_in + sp + 4);
  float4 sgp0 = *(const float4*)(SG_in + sp);
  float4 sgp1 = *(const float4*)(SG_in + sp + 4);
  float4 syn0 = *(const float4*)(Sy_in + sn);
  float4 syn1 = *(const float4*)(Sy_in + sn + 4);
  float4 sgn0 = *(const float4*)(SG_in + sn);
  float4 sgn1 = *(const float4*)(SG_in + sn + 4);
  float4 tz0 = *(const float4*)(tz + c0);
  float4 tz1 = *(const float4*)(tz + c0 + 4);
  // R22 segment-entry correction (pos: z=b, neg: z=2+b)
  int mp = kp & (SEGC - 1), mn = kn & (SEGC - 1);
  size_t ep = ((size_t)b * NSEG + (kp >> 3)) * D1 + c0;
  size_t en = ((size_t)(2 + b) * NSEG + (kn >> 3)) * D1 + c0;
  float4 eyp0 = *(const float4*)(Ey + ep);
  float4 eyp1 = *(const float4*)(Ey + ep + 4);
  float4 egp0 = *(const float4*)(Eg + ep);
  float4 egp1 = *(const float4*)(Eg + ep + 4);
  float4 eyn0 = *(const float4*)(Ey + en);
  float4 eyn1 = *(const float4*)(Ey + en + 4);
  float4 egn0 = *(const float4*)(Eg + en);
  float4 egn1 = *(const float4*)(Eg + en + 4);
  float gmp = __expf((float)(CLEN * mp) * LN_G);   // G_CL^mp
  float gmn = __expf((float)(CLEN * mn) * LN_G);   // G_CL^mn
  float cmp = 16.0f * (float)mp, cmn = 16.0f * (float)mn;

  float syp[8], sgp[8], syn[8], sgn[8], eyp[8], egp[8], eyn[8], egn[8], tza[8];
  auto to8 = [](float4 a, float4 b2, float* o) {
    o[0] = a.x; o[1] = a.y; o[2] = a.z; o[3] = a.w;
    o[4] = b2.x; o[5] = b2.y; o[6] = b2.z; o[7] = b2.w;
  };
  to8(syp0, syp1, syp); to8(sgp0, sgp1, sgp);
  to8(syn0, syn1, syn); to8(sgn0, sgn1, sgn);
  to8(eyp0, eyp1, eyp); to8(egp0, egp1, egp);
  to8(eyn0, eyn1, eyn); to8(egn0, egn1, egn);
  to8(tz0, tz1, tza);
  unsigned int wl[4] = {pyl.x, pyl.y, pyl.z, pyl.w};
  unsigned int wn_[4] = {pyn.x, pyn.y, pyn.z, pyn.w};
  unsigned int wv[4] = {pv.x, pv.y, pv.z, pv.w};
  unsigned int wu[4] = {pu.x, pu.y, pu.z, pu.w};
  float ylv[8], ynv[8], vvv[8], uvv[8];
#pragma unroll
  for (int k = 0; k < 4; ++k) {
    ylv[2 * k] = bflo(wl[k]); ylv[2 * k + 1] = bfhi(wl[k]);
    ynv[2 * k] = bflo(wn_[k]); ynv[2 * k + 1] = bfhi(wn_[k]);
    vvv[2 * k] = bflo(wv[k]); vvv[2 * k + 1] = bfhi(wv[k]);
    uvv[2 * k] = bflo(wu[k]); uvv[2 * k + 1] = bfhi(wu[k]);
  }
  unsigned short g[8];
#pragma unroll
  for (int j = 0; j < 8; ++j) {
    float sypj = syp[j] + gmp * (eyp[j] + cmp * egp[j]);
    float sgpj = sgp[j] + gmp * egp[j];
    float synj = syn[j] + gmn * (eyn[j] + cmn * egn[j]);
    float sgnj = sgn[j] + gmn * egn[j];
    float yv = ylv[j] + gp * (sypj + dpD * sgpj) + ynv[j] + gn * (synj + dnD * sgnj);
    g[j] = f2bf(uvv[j] * (yv + tza[j] * vvv[j]));
  }
  uint4 og;
  og.x = (unsigned int)g[0] | ((unsigned int)g[1] << 16);
  og.y = (unsigned int)g[2] | ((unsigned int)g[3] << 16);
  og.z = (unsigned int)g[4] | ((unsigned int)g[5] << 16);
  og.w = (unsigned int)g[6] | ((unsigned int)g[7] << 16);
  *(uint4*)(G + ix) = og;
}

// ---------------------------------------------------------------------------
extern "C" void kernel_launch(void* const* d_in, const int* in_sizes, int n_in,
                              void* d_out, int out_size, void* d_ws, size_t ws_size,
                              hipStream_t stream) {
  const float* x      = (const float*)d_in[0];
  const float* Wu     = (const float*)d_in[1];
  const float* bu     = (const float*)d_in[2];
  const float* Wv     = (const float*)d_in[3];
  const float* bv     = (const float*)d_in[4];
  const float* Wo     = (const float*)d_in[5];
  const float* bo     = (const float*)d_in[6];
  const float* a_pos  = (const float*)d_in[7];
  const float* b_pos  = (const float*)d_in[8];
  const float* a_neg  = (const float*)d_in[9];
  const float* b_neg  = (const float*)d_in[10];
  const float* t_zero = (const float*)d_in[11];
  float* out = (float*)d_out;

  char* ws = (char*)d_ws;
  unsigned short* x_bf  = (unsigned short*)ws; ws += (size_t)MROWS * DM * 2;        //  8 MB
  unsigned short* u_ws  = (unsigned short*)ws; ws += (size_t)MROWS * D1 * 2;        // 16 MB (g in-place)
  unsigned short* Vp    = (unsigned short*)ws; ws += (size_t)BB * VPROWS * D1 * 2;  // 48 MB padded V
  unsigned short* ypl   = (unsigned short*)ws; ws += (size_t)MROWS * D1 * 2;        // 16 MB
  unsigned short* ynl   = (unsigned short*)ws; ws += (size_t)MROWS * D1 * 2;        // 16 MB
  unsigned short* WoT   = (unsigned short*)ws; ws += (size_t)DM * D1 * 2;           //  4 MB (dedicated)
  float* dtp   = (float*)ws; ws += (size_t)H * NTAP * HD * 4;                       // 229 KB (fp32!)
  float* dtn   = (float*)ws; ws += (size_t)H * NTAP * HD * 4;
  float* Sy_in = (float*)ws; ws += (size_t)4 * NCHUNK * D1 * 4;                     // 4 MB each
  float* SG_in = (float*)ws; ws += (size_t)4 * NCHUNK * D1 * 4;
  unsigned short* zrow = (unsigned short*)ws; ws += (size_t)D1 * 2;                 // 4 KB zero-row
  float* Xy = (float*)ws; ws += (size_t)4 * NSEG * D1 * 4;                          // 512 KB each [R22]
  float* Xg = (float*)ws; ws += (size_t)4 * NSEG * D1 * 4;
  float* Ey = (float*)ws; ws += (size_t)4 * NSEG * D1 * 4;
  float* Eg = (float*)ws; ws += (size_t)4 * NSEG * D1 * 4;
  // exit-state arrays alias x_bf (dead after the uv-gemm, 8 MB = exactly fits)
  float* Sy_ex = (float*)x_bf;
  float* SG_ex = (float*)x_bf + (size_t)4 * NCHUNK * D1;
  // uv weight buffer aliases ypl (disjoint lifetime, stream-ordered)
  unsigned short* WT2 = ypl;

  dim3 tb256(256);
  // fused prep: weights + kdtab + x->bf16 + zero-row (ONE dispatch) [R25]
  wprep_kernel<<<dim3(WPREP_BLKS), tb256, 0, stream>>>(
      Wu, Wv, Wo, WT2, WoT, a_pos, b_pos, a_neg, b_neg, dtp, dtn, x, x_bf, zrow);
  // fused u|v gemm: Bt = [WuT ; WvT] (N = 4096), 256x256 tiles [R16/R19]
  gemm_uv8<<<dim3(16, 16), dim3(512), 0, stream>>>(x_bf, WT2, bu, bv, u_ws, Vp);
  // IIR conv: chunked scans [R18] -> segmented state scan [R22] -> combine
  scan_chunks<<<dim3(D1 / 512, NCHUNK, 4), tb256, 0, stream>>>(Vp, zrow, dtp, dtn, ypl, ynl, Sy_ex, SG_ex);
  state_scan2<<<dim3(4 * NSEG * D1 / 256), tb256, 0, stream>>>(Sy_ex, SG_ex, Sy_in, SG_in, Xy, Xg);
  seg_scan<<<dim3(4 * D1 / 256), tb256, 0, stream>>>(Xy, Xg, Ey, Eg);
  combine_kernel<<<dim3((size_t)MROWS * D1 / 2048), tb256, 0, stream>>>(
      ypl, ynl, Vp, Sy_in, SG_in, Ey, Eg, t_zero, u_ws, u_ws);
  // out = g @ Wo + bo (fp32), 128x128 counted-vmcnt schedule [R21]
  gemm_out2<<<dim3(8, 32), dim3(512), 0, stream>>>(u_ws, WoT, bo, out);
}

// Round 12
// 249.536 us; speedup vs baseline: 1.0413x; 1.0413x over previous
//
#include <hip/hip_runtime.h>
#include <hip/hip_bf16.h>
#include <stdint.h>
#include <stddef.h>

// Problem constants (fixed by the reference)
#define BB 2
#define NSEQ 2048
#define DM 1024
#define H 16
#define HD 128
#define D1 2048
#define NKI 16
#define RANKI 32
#define MROWS (BB * NSEQ)   // 4096 rows for all GEMMs
#define VPROWS 6144         // 2048 zero-pad | 2048 data | 2048 zero-pad
#define NTAP 28
#define NPAIR 13
#define NCHUNK 128
#define CLEN 16
#define NSEG 16             // R22: segments in the chunk-state scan
#define SEGC (NCHUNK / NSEG)   // 8 chunks per segment
#define GAMMA_F 0.999f
#define G_CL 0.9841201f     // 0.999^16 (chunk-length homogeneous decay)
#define G_SC8 0.87979895f   // 0.999^128 = G_CL^8 (segment-length decay)
#define LN_G (-1.00050033e-3f)

// NOTE: delta must remain fp32 everywhere [R9]. No 32x32x16 MFMA [R13].
// LEDGERS (do not re-open without new evidence):
//  SCAN: R18 zero-row redirect = best (~48.5us). R17 branch-skip FAILED,
//    R19 2-chunk MLP NEUTRAL, R20 explicit pipeline FAILED. Parked.
//  UV GEMM: gemm_uv8 256^2/BK64/8-wave counted-vmcnt = best (~46us).
//    R15 neutral, R23 ring-3 REGRESSED. Per-wave MFMA/barrier dominates.
//  OUT GEMM: gemm_out2 128^2/8-wave = best (~30us). R24 out3 REGRESSED.
//  COMBINE: R22 4-ch/thread = best. R25 8-ch REGRESSED (~+6us bundle):
//    2x register state on a BW-bound kernel -> occupancy loss (R20 shape).
// R22 WIN: segmented state scan. R25's prep-into-wprep merge KEPT (this
// round isolates it as the single variable vs the R22 baseline).
__device__ constexpr int TAPS[NTAP] = {
  1, 2, 138, 139, 274, 275, 411, 412, 547, 548, 684,
  820, 821, 956, 957, 1093, 1094, 1229, 1230, 1366,
  1502, 1503, 1638, 1639, 1775, 1776, 1911, 1912};
__device__ constexpr int LEADL[NPAIR] = {1, 138, 274, 411, 547, 820, 956, 1093, 1229, 1502, 1638, 1775, 1911};
__device__ constexpr int LEADI[NPAIR] = {0, 2, 4, 6, 8, 11, 13, 15, 17, 20, 22, 24, 26};
#define SGL0_L 684
#define SGL0_I 10
#define SGL1_L 1366
#define SGL1_I 19

typedef short short8 __attribute__((ext_vector_type(8)));
typedef float floatx4 __attribute__((ext_vector_type(4)));

__device__ __forceinline__ float bf2f(unsigned short u) {
  union { unsigned int i; float f; } v; v.i = ((unsigned int)u) << 16; return v.f;
}
__device__ __forceinline__ unsigned short f2bf(float f) {
  union { float f; unsigned int i; } v; v.f = f;
  unsigned int r = (v.i + 0x7FFFu + ((v.i >> 16) & 1u)) >> 16;
  return (unsigned short)r;
}
__device__ __forceinline__ float bflo(unsigned int p) {
  union { unsigned int i; float f; } v; v.i = p << 16; return v.f;
}
__device__ __forceinline__ float bfhi(unsigned int p) {
  union { unsigned int i; float f; } v; v.i = p & 0xffff0000u; return v.f;
}
// async 16B global->LDS DMA: lane i lands at (wave-uniform) l + i*16 bytes
__device__ __forceinline__ void async16(const unsigned short* g, unsigned short* l) {
  __builtin_amdgcn_global_load_lds(
      (const __attribute__((address_space(1))) unsigned int*)g,
      (__attribute__((address_space(3))) unsigned int*)l, 16, 0, 0);
}

#define CVT4 (MROWS * DM / 4)            // 1048576 float4->ushort4 units
#define WPREP_BLKS (6176 + CVT4 / 256 + 1)   // 10273

// ---- K(l) = interp(kind, l) * gamma^l on an LDS copy of kind --------------
__device__ __forceinline__ float KinterpL(const float* kk, int l, int d) {
  if (l < 1) return 0.0f;   // l > 2047 never queried (max tap 1912)
  float p = (float)(l - 1) * (15.0f / 2046.0f);
  int lo = (int)p; if (lo > 15) lo = 15;
  int hi = lo + 1; if (hi > 15) hi = 15;
  float w = p - (float)lo;
  float v = kk[lo * HD + d] * (1.0f - w) + kk[hi * HD + d] * w;
  return v * __powf(GAMMA_F, (float)l);
}

// ---- fused prep: Wo^T | Wu/Wv^T | kdtab | x->bf16 + zero-row [R25] --------
// blockIdx.x: [0,2048) Wo tiles; [2048,6144) uv tiles; [6144,6176) kdtab;
// [6176, WPREP_BLKS) x-convert + 4KB zero-row.
__global__ __launch_bounds__(256) void wprep_kernel(const float* __restrict__ Wu,
                                                    const float* __restrict__ Wv,
                                                    const float* __restrict__ Wo,
                                                    unsigned short* __restrict__ WT2,
                                                    unsigned short* __restrict__ WoT,
                                                    const float* __restrict__ ap,
                                                    const float* __restrict__ bp,
                                                    const float* __restrict__ an,
                                                    const float* __restrict__ bn,
                                                    float* __restrict__ dtp,
                                                    float* __restrict__ dtn,
                                                    const float* __restrict__ x,
                                                    unsigned short* __restrict__ x_bf,
                                                    unsigned short* __restrict__ zrow) {
  int blk = blockIdx.x;
  int tid = threadIdx.x;
  if (blk < 6144) {
    __shared__ unsigned short t[32][33];
    const float* in; unsigned short* out;
    int rows, cols, bx, by;
    if (blk < 2048) {           // Wo [D1][DM] -> WoT [DM][D1]
      in = Wo; out = WoT; rows = D1; cols = DM;
      bx = (blk & 31) * 32; by = (blk >> 5) * 32;
    } else {                    // Wu/Wv [DM][D1] -> WT2 [2*D1][DM]
      int local = blk - 2048;
      int z = local >> 11, l2 = local & 2047;
      in = z ? Wv : Wu; out = WT2 + (size_t)z * D1 * DM;
      rows = DM; cols = D1;
      bx = (l2 & 63) * 32; by = (l2 >> 6) * 32;
    }
    int tx = tid & 31, ty = tid >> 5;   // (32,8) flattened
#pragma unroll
    for (int j = 0; j < 32; j += 8)
      t[ty + j][tx] = f2bf(in[(size_t)(by + ty + j) * cols + bx + tx]);
    __syncthreads();
#pragma unroll
    for (int j = 0; j < 32; j += 8)
      out[(size_t)(bx + ty + j) * rows + by + tx] = t[tx][ty + j];
  } else if (blk < 6176) {      // kdtab: 32 blocks = (h, dir)
    __shared__ float kk[NKI * HD];  // 8 KB
    int e0 = blk - 6144;
    int h = e0 & 15, dir = e0 >> 4;
    const float* a = (dir ? an : ap) + h * NKI * RANKI;
    const float* b = (dir ? bn : bp) + h * RANKI * HD;
    for (int e = tid; e < NKI * HD; e += 256) {
      int k = e >> 7, d = e & 127;
      float s = 0.0f;
#pragma unroll
      for (int r = 0; r < RANKI; ++r) s += a[k * RANKI + r] * b[r * HD + d];
      kk[e] = s;
    }
    __syncthreads();
    float* dt = (dir ? dtn : dtp) + (size_t)h * NTAP * HD;
    for (int e = tid; e < NTAP * HD; e += 256) {
      int j = e >> 7, d = e & 127;
      int l = TAPS[j];
      float K0 = KinterpL(kk, l, d);
      float K1 = KinterpL(kk, l - 1, d);
      float K2 = KinterpL(kk, l - 2, d);
      dt[e] = K0 - 2.0f * GAMMA_F * K1 + (GAMMA_F * GAMMA_F) * K2;
    }
  } else {                      // x fp32->bf16 + zero-row [R25 merge]
    int i = (blk - 6176) * 256 + tid;
    if (i < CVT4) {
      float4 f = ((const float4*)x)[i];
      ushort4 o;
      o.x = f2bf(f.x); o.y = f2bf(f.y); o.z = f2bf(f.z); o.w = f2bf(f.w);
      ((ushort4*)x_bf)[i] = o;
    } else {
      int j = i - CVT4;
      if (j < 256) {
        uint4 z; z.x = z.y = z.z = z.w = 0u;
        ((uint4*)zrow)[j] = z;
      }
    }
  }
}

// ======== uv GEMM, R16/R19 (proven best): 256x256, BK=64, 8 waves ==========
// C = silu(A @ Bt^T + bias), fused u|v (N=4096): n0>=2048 -> Vp row-remapped.
// LDS: 2 K-tile buffers x (A 256x64 | B 256x64) bf16 = 128 KB, 1 block/CU.
// Swizzle (both-sides, involution): stage src col ((lane&7)^srow)*8, read
// chunk (kk*4+q)^(l16&7). B-frags hoisted (mh-invariant). 64 MFMA/wave/tile.
__global__ __launch_bounds__(512) void gemm_uv8(const unsigned short* __restrict__ A,
                                                const unsigned short* __restrict__ Bt,
                                                const float* __restrict__ bu,
                                                const float* __restrict__ bv,
                                                unsigned short* __restrict__ U,
                                                unsigned short* __restrict__ Vp) {
  __shared__ unsigned short lds[65536];   // 128 KB
  constexpr int K = DM;        // 1024
  constexpr int NT = K / 64;   // 16 K-tiles
  // bijective XCD swizzle: 256 blocks = 8 XCDs x 32
  int lin = blockIdx.y * 16 + blockIdx.x;
  int swz = (lin & 7) * 32 + (lin >> 3);
  int n0 = (swz & 15) * 256;
  int m0 = (swz >> 4) * 256;
  int tid = threadIdx.x;
  int lane = tid & 63, w = tid >> 6;
  int wm = w >> 2, wn = w & 3;            // 2M x 4N wave grid
  int q = lane >> 4, l16 = lane & 15;
  // ---- staging addressing (pre-swizzled global source) ----
  int srow = lane >> 3;                       // 0..7
  int soff = ((lane & 7) ^ srow) << 3;        // swizzled 8-elem chunk
  const unsigned short* Ab = A + (size_t)(m0 + w * 8 + srow) * K + soff;
  const unsigned short* Bb = Bt + (size_t)(n0 + w * 8 + srow) * K + soff;
  unsigned aoff0 = w * 512;                   // elems; +p*16384; +4096 per 64 rows
  unsigned boff0 = 32768u + w * 512;
  // ---- read addressing ----
  int swk0 = (q ^ (l16 & 7)) << 3;            // kk=0 chunk offset (elems)
  int swk1 = ((4 | q) ^ (l16 & 7)) << 3;      // kk=1
  int pAr = wm * 8192;                        // my A half slot (+p*16384)
  int pBr = 32768 + (wn >> 1) * 8192;         // my B half slot (+p*16384)
  int rB0 = (wn & 1) * 64;                    // row base within B half

  floatx4 acc[8][4];
#pragma unroll
  for (int f = 0; f < 8; ++f)
#pragma unroll
    for (int g = 0; g < 4; ++g) acc[f][g] = (floatx4){0.f, 0.f, 0.f, 0.f};

  auto stage = [&](int p, int t) {
    const unsigned short* a = Ab + t * 64;
    const unsigned short* b = Bb + t * 64;
    unsigned ao = aoff0 + p * 16384;
    unsigned bo = boff0 + p * 16384;
    async16(a,               &lds[ao]);
    async16(a + (size_t)64 * K,  &lds[ao + 4096]);
    async16(a + (size_t)128 * K, &lds[ao + 8192]);
    async16(a + (size_t)192 * K, &lds[ao + 12288]);
    async16(b,               &lds[bo]);
    async16(b + (size_t)64 * K,  &lds[bo + 4096]);
    async16(b + (size_t)128 * K, &lds[bo + 8192]);
    async16(b + (size_t)192 * K, &lds[bo + 12288]);
  };

  // prologue: tiles 0 and 1 in flight; wait for tile 0 everywhere
  stage(0, 0);
  stage(1, 1);
  asm volatile("s_waitcnt vmcnt(8)" ::: "memory");
  __builtin_amdgcn_s_barrier();

  for (int t = 0; t < NT; ++t) {
    int p = t & 1;
    const unsigned short* As = &lds[pAr + p * 16384];
    const unsigned short* Bs = &lds[pBr + p * 16384];
    short8 bfr[4][2];
#pragma unroll
    for (int g = 0; g < 4; ++g) {
      int rh = (rB0 + g * 16 + l16) * 64;
      bfr[g][0] = *(const short8*)(Bs + rh + swk0);
      bfr[g][1] = *(const short8*)(Bs + rh + swk1);
    }
#pragma unroll
    for (int mh = 0; mh < 2; ++mh) {
      short8 af[4][2];
#pragma unroll
      for (int f = 0; f < 4; ++f) {
        int rh = ((mh * 4 + f) * 16 + l16) * 64;
        af[f][0] = *(const short8*)(As + rh + swk0);
        af[f][1] = *(const short8*)(As + rh + swk1);
      }
      __builtin_amdgcn_s_setprio(1);
#pragma unroll
      for (int f = 0; f < 4; ++f)
#pragma unroll
        for (int g = 0; g < 4; ++g) {
          acc[mh * 4 + f][g] = __builtin_amdgcn_mfma_f32_16x16x32_bf16(
              af[f][0], bfr[g][0], acc[mh * 4 + f][g], 0, 0, 0);
          acc[mh * 4 + f][g] = __builtin_amdgcn_mfma_f32_16x16x32_bf16(
              af[f][1], bfr[g][1], acc[mh * 4 + f][g], 0, 0, 0);
        }
      __builtin_amdgcn_s_setprio(0);
    }
    if (t == NT - 1) break;
    asm volatile("" ::: "memory");          // keep LDS reads above barrier1
    __builtin_amdgcn_s_barrier();           // all reads of buf p done
    if (t + 2 < NT) {
      stage(p, t + 2);                      // refill freed buffer
      asm volatile("s_waitcnt vmcnt(8)" ::: "memory");  // tile t+1 landed (mine)
    } else {
      asm volatile("s_waitcnt vmcnt(0)" ::: "memory");  // final drain
    }
    __builtin_amdgcn_s_barrier();           // everyone's tile t+1 landed
  }

  // epilogue: D[row = q*4 + r][col = l16] per 16x16 frag (verified mapping)
  int isv = (n0 >= 2048);
  const float* bias = isv ? bv : bu;
#pragma unroll
  for (int f = 0; f < 8; ++f) {
#pragma unroll
    for (int g = 0; g < 4; ++g) {
      int n = n0 + wn * 64 + g * 16 + l16;
      int nc = isv ? (n - 2048) : n;
      float bsv = bias[nc];
#pragma unroll
      for (int r = 0; r < 4; ++r) {
        int m = m0 + wm * 128 + f * 16 + q * 4 + r;
        float val = acc[f][g][r] + bsv;
        val = val / (1.0f + __expf(-val));
        if (isv) {
          size_t mrow = (size_t)(2048 + m + ((m >> 11) << 12));  // padded-V row
          Vp[mrow * 2048 + nc] = f2bf(val);
        } else {
          U[(size_t)m * 2048 + nc] = f2bf(val);
        }
      }
    }
  }
}

// ======== out GEMM, R21 (proven best): 128x128, BK=64, 8 waves =============
// C(fp32) = A @ Bt^T + bias. M=4096 N=1024 K=2048. 2-buf LDS (64 KB),
// stage(t+2) at boundary, vmcnt(4), both-sides XOR swizzle, XCD swizzle.
// Wave grid 4M x 2N; wave output 32x64 (acc[2][4]).
__global__ __launch_bounds__(512) void gemm_out2(const unsigned short* __restrict__ A,
                                                 const unsigned short* __restrict__ Bt,
                                                 const float* __restrict__ bias,
                                                 float* __restrict__ C) {
  __shared__ unsigned short lds[32768];   // 64 KB
  constexpr int K = D1;        // 2048
  constexpr int NT = K / 64;   // 32 K-tiles
  // bijective XCD swizzle: 256 blocks = 8 XCDs x 32
  int lin = blockIdx.y * 8 + blockIdx.x;     // grid (8, 32)
  int swz = (lin & 7) * 32 + (lin >> 3);
  int n0 = (swz & 7) * 128;                  // 8 n-tiles
  int m0 = (swz >> 3) * 128;                 // 32 m-tiles
  int tid = threadIdx.x;
  int lane = tid & 63, w = tid >> 6;
  int wm = w >> 1, wn = w & 1;               // 4M x 2N wave grid
  int q = lane >> 4, l16 = lane & 15;
  // staging (pre-swizzled global source)
  int srow = lane >> 3;
  int soff = ((lane & 7) ^ srow) << 3;
  const unsigned short* Ab = A + (size_t)(m0 + w * 8 + srow) * K + soff;
  const unsigned short* Bb = Bt + (size_t)(n0 + w * 8 + srow) * K + soff;
  unsigned aoff0 = w * 512;                  // +p*8192; +4096 per 64 rows
  unsigned boff0 = 16384u + w * 512;
  // read addressing
  int swk0 = (q ^ (l16 & 7)) << 3;
  int swk1 = ((4 | q) ^ (l16 & 7)) << 3;

  floatx4 acc[2][4];
#pragma unroll
  for (int f = 0; f < 2; ++f)
#pragma unroll
    for (int g = 0; g < 4; ++g) acc[f][g] = (floatx4){0.f, 0.f, 0.f, 0.f};

  auto stage = [&](int p, int t) {
    const unsigned short* a = Ab + t * 64;
    const unsigned short* b = Bb + t * 64;
    unsigned ao = aoff0 + p * 8192;
    unsigned bo = boff0 + p * 8192;
    async16(a,                  &lds[ao]);
    async16(a + (size_t)64 * K, &lds[ao + 4096]);
    async16(b,                  &lds[bo]);
    async16(b + (size_t)64 * K, &lds[bo + 4096]);
  };

  stage(0, 0);
  stage(1, 1);
  asm volatile("s_waitcnt vmcnt(4)" ::: "memory");
  __builtin_amdgcn_s_barrier();

  for (int t = 0; t < NT; ++t) {
    int p = t & 1;
    const unsigned short* As = &lds[p * 8192];
    const unsigned short* Bs = &lds[16384 + p * 8192];
    short8 af[2][2], bfr[4][2];
#pragma unroll
    for (int g = 0; g < 4; ++g) {
      int rh = (wn * 64 + g * 16 + l16) * 64;
      bfr[g][0] = *(const short8*)(Bs + rh + swk0);
      bfr[g][1] = *(const short8*)(Bs + rh + swk1);
    }
#pragma unroll
    for (int f = 0; f < 2; ++f) {
      int rh = (wm * 32 + f * 16 + l16) * 64;
      af[f][0] = *(const short8*)(As + rh + swk0);
      af[f][1] = *(const short8*)(As + rh + swk1);
    }
    __builtin_amdgcn_s_setprio(1);
#pragma unroll
    for (int f = 0; f < 2; ++f)
#pragma unroll
      for (int g = 0; g < 4; ++g) {
        acc[f][g] = __builtin_amdgcn_mfma_f32_16x16x32_bf16(
            af[f][0], bfr[g][0], acc[f][g], 0, 0, 0);
        acc[f][g] = __builtin_amdgcn_mfma_f32_16x16x32_bf16(
            af[f][1], bfr[g][1], acc[f][g], 0, 0, 0);
      }
    __builtin_amdgcn_s_setprio(0);
    if (t == NT - 1) break;
    asm volatile("" ::: "memory");
    __builtin_amdgcn_s_barrier();           // all reads of buf p done
    if (t + 2 < NT) {
      stage(p, t + 2);
      asm volatile("s_waitcnt vmcnt(4)" ::: "memory");  // tile t+1 landed (mine)
    } else {
      asm volatile("s_waitcnt vmcnt(0)" ::: "memory");
    }
    __builtin_amdgcn_s_barrier();           // everyone's tile t+1 landed
  }

  // epilogue: D[row = q*4 + r][col = l16] per 16x16 frag
#pragma unroll
  for (int f = 0; f < 2; ++f) {
#pragma unroll
    for (int g = 0; g < 4; ++g) {
      int n = n0 + wn * 64 + g * 16 + l16;
      float bsv = bias[n];
#pragma unroll
      for (int r = 0; r < 4; ++r) {
        int m = m0 + wm * 32 + f * 16 + q * 4 + r;
        C[(size_t)m * DM + n] = acc[f][g][r] + bsv;
      }
    }
  }
}

// ---------------- chunked IIR scan (phase A) -------------------------------
// R18 VERBATIM (best measured: ~48.5us). Unconditional loads; OOB rows ->
// shared zero-row (uniform base select). Do not re-schedule [ledger].
__global__ __launch_bounds__(256, 1) void scan_chunks(const unsigned short* __restrict__ Vp,
                                                      const unsigned short* __restrict__ zr,
                                                      const float* __restrict__ dp,
                                                      const float* __restrict__ dn,
                                                      unsigned short* __restrict__ ypl,
                                                      unsigned short* __restrict__ ynl,
                                                      float* __restrict__ Sy_ex,
                                                      float* __restrict__ SG_ex) {
  int z = blockIdx.z;            // dir*2 + b
  int dir = z >> 1, b = z & 1;
  int chunk = blockIdx.y;
  int c0 = blockIdx.x * 512 + threadIdx.x * 2;   // two channels per thread
  int h = c0 >> 7, d = c0 & 127;
  const float* dt = (dir ? dn : dp) + ((size_t)h * NTAP) * HD + d;
  float2 dreg[NTAP];
#pragma unroll
  for (int j = 0; j < NTAP; ++j) dreg[j] = *(const float2*)(dt + j * HD);
  // uniform data-region row-0 base (without the per-lane c0)
  const unsigned short* Vd = Vp + (size_t)b * VPROWS * D1 + (size_t)2048 * D1;
  unsigned short* yl = (dir ? ynl : ypl) + (size_t)b * NSEQ * D1 + c0;
  float sy0 = 0.f, sy1 = 0.f, sg0 = 0.f, sg1 = 0.f;
  float carry0[NPAIR], carry1[NPAIR];
  if (!dir) {
    int t0 = chunk * CLEN;
#pragma unroll
    for (int p = 0; p < NPAIR; ++p) {
      int tr = t0 - 1 - LEADL[p];
      const unsigned short* rb = (tr >= 0) ? (Vd + (size_t)tr * D1) : zr;
      unsigned int pk = *(const unsigned int*)(rb + c0);
      carry0[p] = bflo(pk); carry1[p] = bfhi(pk);
    }
    for (int i = 0; i < CLEN; ++i) {
      int t = t0 + i;
      float F0 = 0.f, F1 = 0.f;
#pragma unroll
      for (int p = 0; p < NPAIR; ++p) {
        int tr = t - LEADL[p];
        const unsigned short* rb = (tr >= 0) ? (Vd + (size_t)tr * D1) : zr;
        unsigned int pk = *(const unsigned int*)(rb + c0);
        float vl0 = bflo(pk), vl1 = bfhi(pk);
        F0 += dreg[LEADI[p]].x * vl0 + dreg[LEADI[p] + 1].x * carry0[p];
        F1 += dreg[LEADI[p]].y * vl1 + dreg[LEADI[p] + 1].y * carry1[p];
        carry0[p] = vl0; carry1[p] = vl1;
      }
      {
        int tr = t - SGL0_L;
        const unsigned short* rb = (tr >= 0) ? (Vd + (size_t)tr * D1) : zr;
        unsigned int pk = *(const unsigned int*)(rb + c0);
        F0 += dreg[SGL0_I].x * bflo(pk); F1 += dreg[SGL0_I].y * bfhi(pk);
      }
      {
        int tr = t - SGL1_L;
        const unsigned short* rb = (tr >= 0) ? (Vd + (size_t)tr * D1) : zr;
        unsigned int pk = *(const unsigned int*)(rb + c0);
        F0 += dreg[SGL1_I].x * bflo(pk); F1 += dreg[SGL1_I].y * bfhi(pk);
      }
      sg0 = GAMMA_F * sg0 + F0; sy0 = GAMMA_F * sy0 + sg0;
      sg1 = GAMMA_F * sg1 + F1; sy1 = GAMMA_F * sy1 + sg1;
      unsigned int pack = (unsigned int)f2bf(sy0) | ((unsigned int)f2bf(sy1) << 16);
      *(unsigned int*)(yl + (size_t)t * D1) = pack;
    }
  } else {
    int tstart = (NSEQ - 1) - chunk * CLEN;        // reversed time
#pragma unroll
    for (int p = 0; p < NPAIR; ++p) {
      int tr = tstart + 1 + LEADL[p];
      const unsigned short* rb = (tr <= NSEQ - 1) ? (Vd + (size_t)tr * D1) : zr;
      unsigned int pk = *(const unsigned int*)(rb + c0);
      carry0[p] = bflo(pk); carry1[p] = bfhi(pk);
    }
    for (int i = 0; i < CLEN; ++i) {
      int t = tstart - i;
      float F0 = 0.f, F1 = 0.f;
#pragma unroll
      for (int p = 0; p < NPAIR; ++p) {
        int tr = t + LEADL[p];
        const unsigned short* rb = (tr <= NSEQ - 1) ? (Vd + (size_t)tr * D1) : zr;
        unsigned int pk = *(const unsigned int*)(rb + c0);
        float vl0 = bflo(pk), vl1 = bfhi(pk);
        F0 += dreg[LEADI[p]].x * vl0 + dreg[LEADI[p] + 1].x * carry0[p];
        F1 += dreg[LEADI[p]].y * vl1 + dreg[LEADI[p] + 1].y * carry1[p];
        carry0[p] = vl0; carry1[p] = vl1;
      }
      {
        int tr = t + SGL0_L;
        const unsigned short* rb = (tr <= NSEQ - 1) ? (Vd + (size_t)tr * D1) : zr;
        unsigned int pk = *(const unsigned int*)(rb + c0);
        F0 += dreg[SGL0_I].x * bflo(pk); F1 += dreg[SGL0_I].y * bfhi(pk);
      }
      {
        int tr = t + SGL1_L;
        const unsigned short* rb = (tr <= NSEQ - 1) ? (Vd + (size_t)tr * D1) : zr;
        unsigned int pk = *(const unsigned int*)(rb + c0);
        F0 += dreg[SGL1_I].x * bflo(pk); F1 += dreg[SGL1_I].y * bfhi(pk);
      }
      sg0 = GAMMA_F * sg0 + F0; sy0 = GAMMA_F * sy0 + sg0;
      sg1 = GAMMA_F * sg1 + F1; sy1 = GAMMA_F * sy1 + sg1;
      unsigned int pack = (unsigned int)f2bf(sy0) | ((unsigned int)f2bf(sy1) << 16);
      *(unsigned int*)(yl + (size_t)t * D1) = pack;
    }
  }
  size_t sidx = ((size_t)z * NCHUNK + chunk) * D1 + c0;
  Sy_ex[sidx] = sy0; Sy_ex[sidx + 1] = sy1;
  SG_ex[sidx] = sg0; SG_ex[sidx + 1] = sg1;
}

// ------- phase B1 (R22): segment-local chunk-state prefixes ----------------
__global__ __launch_bounds__(256) void state_scan2(const float* __restrict__ Sy_ex,
                                                   const float* __restrict__ SG_ex,
                                                   float* __restrict__ Sy_in,
                                                   float* __restrict__ SG_in,
                                                   float* __restrict__ Xy,
                                                   float* __restrict__ Xg) {
  int idx = blockIdx.x * 256 + threadIdx.x;   // [0, 4*NSEG*D1)
  int c = idx & (D1 - 1);
  int zs = idx >> 11;            // z*NSEG + seg
  int z = zs >> 4, seg = zs & (NSEG - 1);
  float ey = 0.f, eg = 0.f;
#pragma unroll
  for (int m = 0; m < SEGC; ++m) {
    int k = seg * SEGC + m;
    size_t s = ((size_t)z * NCHUNK + k) * D1 + c;
    Sy_in[s] = ey; SG_in[s] = eg;
    float lex = Sy_ex[s], lgx = SG_ex[s];
    ey = lex + G_CL * (ey + (float)CLEN * eg);
    eg = lgx + G_CL * eg;
  }
  size_t xi = (size_t)zs * D1 + c;
  Xy[xi] = ey; Xg[xi] = eg;
}

// ------- phase B2 (R22): scan the 16 segment exits with A^8 ----------------
__global__ __launch_bounds__(256) void seg_scan(const float* __restrict__ Xy,
                                                const float* __restrict__ Xg,
                                                float* __restrict__ Ey,
                                                float* __restrict__ Eg) {
  int idx = blockIdx.x * 256 + threadIdx.x;   // [0, 4*D1)
  int z = idx >> 11, c = idx & (D1 - 1);
  float ey = 0.f, eg = 0.f;
#pragma unroll
  for (int s = 0; s < NSEG; ++s) {
    size_t xi = ((size_t)z * NSEG + s) * D1 + c;
    Ey[xi] = ey; Eg[xi] = eg;
    float xy = Xy[xi], xg = Xg[xi];
    ey = xy + G_SC8 * (ey + 128.0f * eg);
    eg = xg + G_SC8 * eg;
  }
}

// ---------------- combine + gate (phase C), 4 channels/thread [R22 best] ---
// Sy_in/SG_in hold segment-LOCAL prefixes; correction via A^m and segment
// entry states Ey/Eg (L2-resident 512KB arrays):
//   Sy += g^m*(Ey + 16m*Eg), SG += g^m*Eg, g^m = exp(16m*LN_G), m = k&7.
__global__ __launch_bounds__(256) void combine_kernel(const unsigned short* __restrict__ ypl,
                                                      const unsigned short* __restrict__ ynl,
                                                      const unsigned short* __restrict__ Vp,
                                                      const float* __restrict__ Sy_in,
                                                      const float* __restrict__ SG_in,
                                                      const float* __restrict__ Ey,
                                                      const float* __restrict__ Eg,
                                                      const float* __restrict__ tz,
                                                      const unsigned short* __restrict__ U,
                                                      unsigned short* __restrict__ G) {
  int e = blockIdx.x * 256 + threadIdx.x;     // quad index over [b][t][c/4]
  int cq = e & (D1 / 4 - 1);
  int c0 = cq * 4;
  int r = e >> 9;
  int t = r & (NSEQ - 1);
  int b = r >> 11;
  int kp = t >> 4;  float dpD = (float)((t & 15) + 1);
  int tau = (NSEQ - 1) - t;
  int kn = tau >> 4; float dnD = (float)((tau & 15) + 1);
  float gp = __expf(dpD * LN_G);
  float gn = __expf(dnD * LN_G);
  size_t ix = (size_t)r * D1 + c0;
  size_t sp = ((size_t)(b) * NCHUNK + kp) * D1 + c0;          // z = b (pos)
  size_t sn = ((size_t)(2 + b) * NCHUNK + kn) * D1 + c0;      // z = 2+b (neg)
  uint2 pyl = *(const uint2*)(ypl + ix);
  uint2 pyn = *(const uint2*)(ynl + ix);
  uint2 pv  = *(const uint2*)(Vp + ((size_t)b * VPROWS + 2048 + t) * D1 + c0);
  uint2 pu  = *(const uint2*)(U + ix);
  float4 syp = *(const float4*)(Sy_in + sp);
  float4 sgp = *(const float4*)(SG_in + sp);
  float4 syn = *(const float4*)(Sy_in + sn);
  float4 sgn = *(const float4*)(SG_in + sn);
  float4 tzv = *(const float4*)(tz + c0);
  // R22 segment-entry correction (pos: z=b, neg: z=2+b)
  int mp = kp & (SEGC - 1), mn = kn & (SEGC - 1);
  size_t ep = ((size_t)b * NSEG + (kp >> 3)) * D1 + c0;
  size_t en = ((size_t)(2 + b) * NSEG + (kn >> 3)) * D1 + c0;
  float4 eyp = *(const float4*)(Ey + ep);
  float4 egp = *(const float4*)(Eg + ep);
  float4 eyn = *(const float4*)(Ey + en);
  float4 egn = *(const float4*)(Eg + en);
  float gmp = __expf((float)(CLEN * mp) * LN_G);   // G_CL^mp
  float gmn = __expf((float)(CLEN * mn) * LN_G);   // G_CL^mn
  float cmp = 16.0f * (float)mp, cmn = 16.0f * (float)mn;
  syp.x += gmp * (eyp.x + cmp * egp.x); sgp.x += gmp * egp.x;
  syp.y += gmp * (eyp.y + cmp * egp.y); sgp.y += gmp * egp.y;
  syp.z += gmp * (eyp.z + cmp * egp.z); sgp.z += gmp * egp.z;
  syp.w += gmp * (eyp.w + cmp * egp.w); sgp.w += gmp * egp.w;
  syn.x += gmn * (eyn.x + cmn * egn.x); sgn.x += gmn * egn.x;
  syn.y += gmn * (eyn.y + cmn * egn.y); sgn.y += gmn * egn.y;
  syn.z += gmn * (eyn.z + cmn * egn.z); sgn.z += gmn * egn.z;
  syn.w += gmn * (eyn.w + cmn * egn.w); sgn.w += gmn * egn.w;
  float yv[4], uv[4], vv[4];
  yv[0] = bflo(pyl.x) + gp * (syp.x + dpD * sgp.x) + bflo(pyn.x) + gn * (syn.x + dnD * sgn.x);
  yv[1] = bfhi(pyl.x) + gp * (syp.y + dpD * sgp.y) + bfhi(pyn.x) + gn * (syn.y + dnD * sgn.y);
  yv[2] = bflo(pyl.y) + gp * (syp.z + dpD * sgp.z) + bflo(pyn.y) + gn * (syn.z + dnD * sgn.z);
  yv[3] = bfhi(pyl.y) + gp * (syp.w + dpD * sgp.w) + bfhi(pyn.y) + gn * (syn.w + dnD * sgn.w);
  vv[0] = bflo(pv.x); vv[1] = bfhi(pv.x); vv[2] = bflo(pv.y); vv[3] = bfhi(pv.y);
  uv[0] = bflo(pu.x); uv[1] = bfhi(pu.x); uv[2] = bflo(pu.y); uv[3] = bfhi(pu.y);
  float tza[4] = {tzv.x, tzv.y, tzv.z, tzv.w};
  uint2 og;
  unsigned short g0 = f2bf(uv[0] * (yv[0] + tza[0] * vv[0]));
  unsigned short g1 = f2bf(uv[1] * (yv[1] + tza[1] * vv[1]));
  unsigned short g2 = f2bf(uv[2] * (yv[2] + tza[2] * vv[2]));
  unsigned short g3 = f2bf(uv[3] * (yv[3] + tza[3] * vv[3]));
  og.x = (unsigned int)g0 | ((unsigned int)g1 << 16);
  og.y = (unsigned int)g2 | ((unsigned int)g3 << 16);
  *(uint2*)(G + ix) = og;
}

// ---------------------------------------------------------------------------
extern "C" void kernel_launch(void* const* d_in, const int* in_sizes, int n_in,
                              void* d_out, int out_size, void* d_ws, size_t ws_size,
                              hipStream_t stream) {
  const float* x      = (const float*)d_in[0];
  const float* Wu     = (const float*)d_in[1];
  const float* bu     = (const float*)d_in[2];
  const float* Wv     = (const float*)d_in[3];
  const float* bv     = (const float*)d_in[4];
  const float* Wo     = (const float*)d_in[5];
  const float* bo     = (const float*)d_in[6];
  const float* a_pos  = (const float*)d_in[7];
  const float* b_pos  = (const float*)d_in[8];
  const float* a_neg  = (const float*)d_in[9];
  const float* b_neg  = (const float*)d_in[10];
  const float* t_zero = (const float*)d_in[11];
  float* out = (float*)d_out;

  char* ws = (char*)d_ws;
  unsigned short* x_bf  = (unsigned short*)ws; ws += (size_t)MROWS * DM * 2;        //  8 MB
  unsigned short* u_ws  = (unsigned short*)ws; ws += (size_t)MROWS * D1 * 2;        // 16 MB (g in-place)
  unsigned short* Vp    = (unsigned short*)ws; ws += (size_t)BB * VPROWS * D1 * 2;  // 48 MB padded V
  unsigned short* ypl   = (unsigned short*)ws; ws += (size_t)MROWS * D1 * 2;        // 16 MB
  unsigned short* ynl   = (unsigned short*)ws; ws += (size_t)MROWS * D1 * 2;        // 16 MB
  unsigned short* WoT   = (unsigned short*)ws; ws += (size_t)DM * D1 * 2;           //  4 MB (dedicated)
  float* dtp   = (float*)ws; ws += (size_t)H * NTAP * HD * 4;                       // 229 KB (fp32!)
  float* dtn   = (float*)ws; ws += (size_t)H * NTAP * HD * 4;
  float* Sy_in = (float*)ws; ws += (size_t)4 * NCHUNK * D1 * 4;                     // 4 MB each
  float* SG_in = (float*)ws; ws += (size_t)4 * NCHUNK * D1 * 4;
  unsigned short* zrow = (unsigned short*)ws; ws += (size_t)D1 * 2;                 // 4 KB zero-row
  float* Xy = (float*)ws; ws += (size_t)4 * NSEG * D1 * 4;                          // 512 KB each [R22]
  float* Xg = (float*)ws; ws += (size_t)4 * NSEG * D1 * 4;
  float* Ey = (float*)ws; ws += (size_t)4 * NSEG * D1 * 4;
  float* Eg = (float*)ws; ws += (size_t)4 * NSEG * D1 * 4;
  // exit-state arrays alias x_bf (dead after the uv-gemm, 8 MB = exactly fits)
  float* Sy_ex = (float*)x_bf;
  float* SG_ex = (float*)x_bf + (size_t)4 * NCHUNK * D1;
  // uv weight buffer aliases ypl (disjoint lifetime, stream-ordered)
  unsigned short* WT2 = ypl;

  dim3 tb256(256);
  // fused prep: weights + kdtab + x->bf16 + zero-row (ONE dispatch) [R25]
  wprep_kernel<<<dim3(WPREP_BLKS), tb256, 0, stream>>>(
      Wu, Wv, Wo, WT2, WoT, a_pos, b_pos, a_neg, b_neg, dtp, dtn, x, x_bf, zrow);
  // fused u|v gemm: Bt = [WuT ; WvT] (N = 4096), 256x256 tiles [R16/R19]
  gemm_uv8<<<dim3(16, 16), dim3(512), 0, stream>>>(x_bf, WT2, bu, bv, u_ws, Vp);
  // IIR conv: chunked scans [R18] -> segmented state scan [R22] -> combine
  scan_chunks<<<dim3(D1 / 512, NCHUNK, 4), tb256, 0, stream>>>(Vp, zrow, dtp, dtn, ypl, ynl, Sy_ex, SG_ex);
  state_scan2<<<dim3(4 * NSEG * D1 / 256), tb256, 0, stream>>>(Sy_ex, SG_ex, Sy_in, SG_in, Xy, Xg);
  seg_scan<<<dim3(4 * D1 / 256), tb256, 0, stream>>>(Xy, Xg, Ey, Eg);
  combine_kernel<<<dim3((size_t)MROWS * D1 / 1024), tb256, 0, stream>>>(
      ypl, ynl, Vp, Sy_in, SG_in, Ey, Eg, t_zero, u_ws, u_ws);
  // out = g @ Wo + bo (fp32), 128x128 counted-vmcnt schedule [R21]
  gemm_out2<<<dim3(8, 32), dim3(512), 0, stream>>>(u_ws, WoT, bo, out);
}